// Round 2
// baseline (1291.025 us; speedup 1.0000x reference)
//
#include <hip/hip_runtime.h>

// Native clang vector type — __builtin_nontemporal_* accepts this (HIP float4 is a struct).
typedef float f32x4 __attribute__((ext_vector_type(4)));

// Fused circular-buffer update: one grid-stride kernel copies
//   out_feat[row] = (rel < B) ? features[rel]    : mem_feat[row]
//   out_pred[row] = (rel < B) ? predictions[rel] : mem_pred[row]
//   out_conf[row] = (rel < B) ? confidences[rel] : mem_conf[row]
// where rel = (row - mi) mod M. Branchless source select, 16B vector moves,
// 2x unroll x 2 planes = 4 independent loads + 4 stores in flight per thread,
// nontemporal hints (all streams are single-use; don't pollute L2).
__global__ __launch_bounds__(256)
void fused_update(const f32x4* __restrict__ memf,
                  const f32x4* __restrict__ memp,
                  const f32x4* __restrict__ batf,
                  const f32x4* __restrict__ batp,
                  f32x4* __restrict__ outf,
                  f32x4* __restrict__ outp,
                  const float* __restrict__ memc,
                  const float* __restrict__ batc,
                  float* __restrict__ outc,
                  const int* __restrict__ d_mi,
                  int M, int B, int D4, int shift, int total4) {
    const int mi = *d_mi;
    const int stride = gridDim.x * blockDim.x;
    const int tid0 = blockIdx.x * blockDim.x + threadIdx.x;

    // confidence plane: M floats (one iteration for the first M threads)
    for (int c = tid0; c < M; c += stride) {
        int rel = c - mi; if (rel < 0) rel += M;
        const float* src = (rel < B) ? (batc + rel) : (memc + c);
        __builtin_nontemporal_store(__builtin_nontemporal_load(src), outc + c);
    }

    const int mask = D4 - 1;

    // main planes: total4 f32x4 per plane, both planes per index.
#define BODY(G)                                                              \
    {                                                                        \
        int g_ = (G);                                                        \
        int row_, off_;                                                      \
        if (shift >= 0) { row_ = g_ >> shift; off_ = g_ & mask; }            \
        else            { row_ = g_ / D4;     off_ = g_ - row_ * D4; }       \
        int rel_ = row_ - mi; if (rel_ < 0) rel_ += M;                       \
        int s_ = rel_ * D4 + off_;                                           \
        const f32x4* sf_ = (rel_ < B) ? (batf + s_) : (memf + g_);           \
        const f32x4* sp_ = (rel_ < B) ? (batp + s_) : (memp + g_);           \
        f32x4 vf_ = __builtin_nontemporal_load(sf_);                         \
        f32x4 vp_ = __builtin_nontemporal_load(sp_);                         \
        __builtin_nontemporal_store(vf_, outf + g_);                         \
        __builtin_nontemporal_store(vp_, outp + g_);                         \
    }

    int g = tid0;
    for (; g + stride < total4; g += 2 * stride) {
        BODY(g)
        BODY(g + stride)
    }
    if (g < total4) BODY(g)
#undef BODY
}

// Single block: mean of B confidences + utilization scalar.
__global__ void mean_and_util(const float* __restrict__ conf,
                              const int* __restrict__ d_mi,
                              const int* __restrict__ d_full,
                              float* __restrict__ out_mean,
                              float* __restrict__ out_util,
                              int B, int M) {
    __shared__ float warp_sums[8];
    float s = 0.0f;
    for (int i = threadIdx.x; i < B; i += blockDim.x) s += conf[i];
    #pragma unroll
    for (int off = 32; off > 0; off >>= 1) s += __shfl_down(s, off);
    int lane = threadIdx.x & 63;
    int wave = threadIdx.x >> 6;
    if (lane == 0) warp_sums[wave] = s;
    __syncthreads();
    if (threadIdx.x == 0) {
        int nwaves = (blockDim.x + 63) >> 6;
        float total = 0.0f;
        for (int w = 0; w < nwaves; ++w) total += warp_sums[w];
        out_mean[0] = total / (float)B;

        int mi = *d_mi;
        int ni = (mi + B) % M;
        bool wrapped = (mi + B) >= M;
        bool full = (*d_full != 0) || wrapped;
        out_util[0] = full ? 1.0f : (float)ni / (float)M;
    }
}

extern "C" void kernel_launch(void* const* d_in, const int* in_sizes, int n_in,
                              void* d_out, int out_size, void* d_ws, size_t ws_size,
                              hipStream_t stream) {
    const float* features     = (const float*)d_in[0];
    const float* predictions  = (const float*)d_in[1];
    const float* confidences  = (const float*)d_in[2];
    const float* mem_feat     = (const float*)d_in[3];
    const float* mem_pred     = (const float*)d_in[4];
    const float* mem_conf     = (const float*)d_in[5];
    const int*   d_mi         = (const int*)d_in[6];
    const int*   d_full       = (const int*)d_in[7];

    const int B  = in_sizes[2];          // 4096
    const int MD = in_sizes[3];          // 102,400,000
    const int M  = in_sizes[5];          // 100,000
    const int D  = MD / M;               // 1024
    const int D4 = D / 4;                // 256
    const int total4 = M * D4;           // 25,600,000 f32x4 per plane
    const int shift  = ((D4 & (D4 - 1)) == 0) ? __builtin_ctz(D4) : -1;

    float* out       = (float*)d_out;
    float* out_feat  = out;
    float* out_pred  = out + (size_t)MD;
    float* out_conf  = out + (size_t)2 * MD;
    float* out_mean  = out_conf + M;
    float* out_util  = out_mean + 1;

    const int blocks = 2048;             // 256 CU x 8 blocks, grid-stride

    fused_update<<<blocks, 256, 0, stream>>>(
        (const f32x4*)mem_feat, (const f32x4*)mem_pred,
        (const f32x4*)features, (const f32x4*)predictions,
        (f32x4*)out_feat, (f32x4*)out_pred,
        mem_conf, confidences, out_conf,
        d_mi, M, B, D4, shift, total4);

    mean_and_util<<<1, 256, 0, stream>>>(confidences, d_mi, d_full,
                                         out_mean, out_util, B, M);
}